// Round 6
// baseline (1324.013 us; speedup 1.0000x reference)
//
#include <hip/hip_runtime.h>
#include <hip/hip_bf16.h>

// ---------------------------------------------------------------------------
// GAT (4 layers + fc) on MI355X. CSR-gather formulation (no float atomics).
// flags[0]: float tensors bf16(1)/fp32(0); flags[1]: edges int64(1)/int32(0)
// fp32 internal compute, fp32 output.
// R5: XCD-affinity bucketed csr_fill, parallel scan, templated GEMM with
//     pre-transposed weights, templated+unrolled gather.
// ---------------------------------------------------------------------------

__device__ __forceinline__ float bf2f(unsigned short w) {
    return __uint_as_float(((unsigned int)w) << 16);
}

// --------------------------- dtype detection -------------------------------
__global__ void detect_kernel(const unsigned short* __restrict__ xw,
                              const int* __restrict__ ew,
                              int* __restrict__ flags)
{
    __shared__ int cnt_sane[256];
    __shared__ int cnt_nz[256];
    const int t = threadIdx.x;
    unsigned short w = xw[2 * t];
    int e = (w >> 7) & 0xff;
    cnt_sane[t] = (e >= 110 && e <= 133) ? 1 : 0;
    cnt_nz[t] = (ew[2 * t + 1] != 0) ? 1 : 0;
    __syncthreads();
    if (t == 0) {
        int s = 0, nz = 0;
        for (int i = 0; i < 256; ++i) { s += cnt_sane[i]; nz += cnt_nz[i]; }
        flags[0] = (s >= 128) ? 1 : 0;
        flags[1] = (nz == 0) ? 1 : 0;
    }
}

// --------------------------- param conversion ------------------------------
// Weights are transposed on conversion: W[rows][cols] -> Wt[cols][rows]
struct ParamPtrs {
    const void* src[18];
    int n[18];
    int off[18];
    int rows[18];   // >0: transpose with this row count
    int cols[18];
};

__global__ void convert_params_kernel(ParamPtrs pp, const int* __restrict__ flags,
                                      float* __restrict__ out)
{
    const int b = blockIdx.x;
    const int n = pp.n[b];
    const float* fp = (const float*)pp.src[b];
    const unsigned short* hp = (const unsigned short*)pp.src[b];
    const int bf = flags[0];
    const int rows = pp.rows[b], cols = pp.cols[b];
    float* o = out + pp.off[b];
    for (int i = threadIdx.x; i < n; i += blockDim.x) {
        float v = bf ? bf2f(hp[i]) : fp[i];
        if (rows > 0) o[(i % cols) * rows + (i / cols)] = v;
        else          o[i] = v;
    }
}

// --------------------------- edge extraction -------------------------------
__global__ void extract_edges_kernel(const int* __restrict__ e, const int* __restrict__ flags,
                                     int* __restrict__ srcA, int* __restrict__ dstA,
                                     long long E, long long Et)
{
    long long t = (long long)blockIdx.x * blockDim.x + threadIdx.x;
    if (t >= Et) return;
    int s, d;
    if (t >= E) { s = (int)(t - E); d = s; }
    else if (flags[1]) { s = e[2 * t]; d = e[2 * E + 2 * t]; }
    else               { s = e[t];     d = e[E + t]; }
    srcA[t] = s;
    dstA[t] = d;
}

__global__ void csr_count_kernel(const int* __restrict__ dstA, int* __restrict__ deg,
                                 long long Et)
{
    long long t = (long long)blockIdx.x * blockDim.x + threadIdx.x;
    if (t < Et) atomicAdd(&deg[dstA[t]], 1);
}

// ------------------------------ parallel scan ------------------------------
__global__ void scan_partial_kernel(const int* __restrict__ deg, int* __restrict__ partials,
                                    int N)
{
    __shared__ int sd[256];
    const int t = threadIdx.x;
    const int i = blockIdx.x * 256 + t;
    sd[t] = (i < N) ? deg[i] : 0;
    __syncthreads();
    for (int s = 128; s > 0; s >>= 1) {
        if (t < s) sd[t] += sd[t + s];
        __syncthreads();
    }
    if (t == 0) partials[blockIdx.x] = sd[0];
}

__global__ void scan_mid_kernel(const int* __restrict__ partials, int* __restrict__ pscan,
                                int* __restrict__ rowptr, int NB, int N)
{
    if (threadIdx.x == 0) {
        int a = 0;
        for (int j = 0; j < NB; ++j) { pscan[j] = a; a += partials[j]; }
        rowptr[N] = a;
    }
}

__global__ void scan_write_kernel(const int* __restrict__ deg, const int* __restrict__ pscan,
                                  int* __restrict__ rowptr, int* __restrict__ fillpos, int N)
{
    __shared__ int sd[256];
    const int t = threadIdx.x;
    const int i = blockIdx.x * 256 + t;
    const int v = (i < N) ? deg[i] : 0;
    sd[t] = v;
    __syncthreads();
    for (int off = 1; off < 256; off <<= 1) {
        int x = (t >= off) ? sd[t - off] : 0;
        __syncthreads();
        sd[t] += x;
        __syncthreads();
    }
    const int pos = pscan[blockIdx.x] + sd[t] - v;
    if (i < N) { rowptr[i] = pos; fillpos[i] = pos; }
}

// ------------------------- bucketed CSR fill -------------------------------
// bucket = blockIdx.x & 7 -> round-robin XCD affinity; each bucket's csr_src
// region is dirtied in (heuristically) one XCD L2 -> full-line writebacks.
__global__ __launch_bounds__(256) void csr_fill_bucket_kernel(
    const int* __restrict__ srcA, const int* __restrict__ dstA,
    int* __restrict__ fillpos, int* __restrict__ csr_src,
    long long Et, int chunkSize, int shift)
{
    const int bucket = blockIdx.x & 7;
    const long long c0 = (long long)(blockIdx.x >> 3) * chunkSize;
    const long long c1 = min(c0 + (long long)chunkSize, Et);
    for (long long i = c0 + threadIdx.x; i < c1; i += 256) {
        const int d = dstA[i];
        if ((d >> shift) == bucket) {
            const int pos = atomicAdd(&fillpos[d], 1);
            csr_src[pos] = srcA[i];
        }
    }
}

// ------------------------------- GEMM --------------------------------------
// x:[N,FIN] -> h:[N,FOUT], fused alpha dots. Wt is transposed [FOUT][FIN].
// blockDim=(FOUT, 256/FOUT).
template <int FIN, int FOUT>
__global__ __launch_bounds__(256) void gemm_alpha_kernel(
    const void* __restrict__ xv, const int* __restrict__ flags, int x_ext,
    const float* __restrict__ Wt, const float* __restrict__ a_src,
    const float* __restrict__ a_dst, const float* __restrict__ bias,
    float* __restrict__ h,
    float* __restrict__ alpha_s, float* __restrict__ alpha_d,
    int N, int relu_in, int has_bias)
{
    constexpr int ROWS = 256 / FOUT;
    __shared__ float xs[ROWS * FIN];
    __shared__ float red_s[256];
    __shared__ float red_d[256];

    const int tx = threadIdx.x;
    const int ty = threadIdx.y;
    const int tid = ty * FOUT + tx;
    const long long base_row = (long long)blockIdx.x * ROWS;

    const int xbf = x_ext ? flags[0] : 0;
    const float* xf = (const float*)xv;
    const unsigned short* xh = (const unsigned short*)xv;

    constexpr int total = ROWS * FIN;
    #pragma unroll
    for (int idx = tid; idx < total; idx += 256) {
        const int r = idx / FIN;
        const int c = idx - r * FIN;
        const long long grow = base_row + r;
        float v = 0.f;
        if (grow < N) {
            const long long gi = grow * FIN + c;
            v = xbf ? bf2f(xh[gi]) : xf[gi];
        }
        if (relu_in) v = fmaxf(v, 0.f);
        xs[idx] = v;
    }
    __syncthreads();

    const long long grow = base_row + ty;
    const float4* xs4 = (const float4*)(xs + ty * FIN);
    const float4* wt4 = (const float4*)(Wt + tx * FIN);
    float acc = 0.f;
    #pragma unroll
    for (int k = 0; k < FIN / 4; ++k) {
        const float4 a = xs4[k];
        const float4 b = wt4[k];
        acc += a.x * b.x + a.y * b.y + a.z * b.z + a.w * b.w;
    }
    if (has_bias) acc += bias[tx];
    if (grow < N) h[grow * FOUT + tx] = acc;

    if (alpha_s) {
        red_s[tid] = acc * a_src[tx];
        red_d[tid] = acc * a_dst[tx];
        __syncthreads();
        #pragma unroll
        for (int s = FOUT >> 1; s > 0; s >>= 1) {
            if (tx < s) {
                red_s[tid] += red_s[tid + s];
                red_d[tid] += red_d[tid + s];
            }
            __syncthreads();
        }
        if (tx == 0 && grow < N) {
            alpha_s[grow] = red_s[ty * FOUT];
            alpha_d[grow] = red_d[ty * FOUT];
        }
    }
}

// --------------------------- gather (per-dst wave) -------------------------
// One wave per destination node; softmax + weighted sum in registers.
template <int FOUT>
__global__ __launch_bounds__(256) void gat_gather_kernel(
    const int* __restrict__ rowptr, const int* __restrict__ csr_src,
    const float* __restrict__ as, const float* __restrict__ ad,
    const float* __restrict__ h, const float* __restrict__ bias,
    float* __restrict__ out, int N)
{
    const int wslot = threadIdx.x >> 6;
    const int lane = threadIdx.x & 63;
    const int d = blockIdx.x * 4 + wslot;
    if (d >= N) return;

    const int r0 = rowptr[d];
    const int r1 = rowptr[d + 1];
    const float add = ad[d];

    // pass 1: segment max
    float m = -INFINITY;
    for (int base = r0; base < r1; base += 64) {
        const int e = base + lane;
        if (e < r1) {
            const int s = csr_src[e];
            float v = as[s] + add;
            v = (v > 0.f) ? v : 0.2f * v;
            m = fmaxf(m, v);
        }
    }
    #pragma unroll
    for (int off = 32; off > 0; off >>= 1)
        m = fmaxf(m, __shfl_down(m, off, 64));
    m = __shfl(m, 0, 64);

    // pass 2: exp weights + feature accumulation
    constexpr int epi = (FOUT < 64) ? (64 / FOUT) : 1;
    const int sub = (FOUT < 64) ? (lane / FOUT) : 0;
    const int f   = (FOUT < 64) ? (lane % FOUT) : lane;

    float den = 0.f;
    float acc0 = 0.f, acc1 = 0.f;
    for (int base = r0; base < r1; base += 64) {
        const int e = base + lane;
        float p = 0.f;
        int s = 0;
        if (e < r1) {
            s = csr_src[e];
            float v = as[s] + add;
            v = (v > 0.f) ? v : 0.2f * v;
            p = expf(v - m);
        }
        den += p;
        const int cnt = min(64, r1 - base);
        // unroll 4 edge-groups; OOB slots carry p=0 so over-run is harmless
        for (int j = 0; j < cnt; j += 4 * epi) {
            #pragma unroll
            for (int u = 0; u < 4; ++u) {
                const int jj = j + u * epi + sub;
                const float pj = __shfl(p, jj, 64);
                const int   sj = __shfl(s, jj, 64);
                acc0 += pj * h[(long long)sj * FOUT + f];
                if (FOUT == 128) acc1 += pj * h[(long long)sj * FOUT + f + 64];
            }
        }
    }
    #pragma unroll
    for (int off = 32; off > 0; off >>= 1)
        den += __shfl_down(den, off, 64);
    den = __shfl(den, 0, 64);
    const float inv = 1.f / den;

    if (FOUT == 128) {
        out[(long long)d * 128 + lane]      = bias[lane] + acc0 * inv;
        out[(long long)d * 128 + lane + 64] = bias[lane + 64] + acc1 * inv;
    } else if (FOUT == 64) {
        out[(long long)d * 64 + lane] = bias[lane] + acc0 * inv;
    } else {
        acc0 += __shfl_down(acc0, 32, 64);
        if (lane < 32)
            out[(long long)d * 32 + lane] = bias[lane] + acc0 * inv;
    }
}

// ------------------------------- launch ------------------------------------
extern "C" void kernel_launch(void* const* d_in, const int* in_sizes, int n_in,
                              void* d_out, int out_size, void* d_ws, size_t ws_size,
                              hipStream_t stream)
{
    const int INP = 128;
    const int N = in_sizes[0] / INP;                 // 50000
    const long long E = in_sizes[1] / 2;             // 1600000
    const long long Et = E + N;

    const int Fin[4]  = {128, 32, 64, 128};
    const int Fout[4] = {32, 64, 128, 128};

    // ---- workspace layout (~59 MB) ----
    char* p = (char*)d_ws;
    auto alloc = [&](size_t bytes) {
        char* r = p;
        p += (bytes + 255) & ~(size_t)255;
        return r;
    };
    float* bufH    = (float*)alloc((size_t)N * 128 * sizeof(float));
    float* bufX    = (float*)alloc((size_t)N * 128 * sizeof(float));
    float* as      = (float*)alloc((size_t)N * sizeof(float));
    float* ad      = (float*)alloc((size_t)N * sizeof(float));
    int*   deg     = (int*)  alloc((size_t)N * sizeof(int));
    int*   rowptr  = (int*)  alloc((size_t)(N + 1) * sizeof(int));
    int*   fillpos = (int*)  alloc((size_t)N * sizeof(int));
    int*   csr_src = (int*)  alloc((size_t)Et * sizeof(int));
    int*   pscan   = (int*)  alloc(2 * 256 * sizeof(int));   // partials + scan
    int*   flags   = (int*)  alloc(64);
    float* params  = (float*)alloc(64 * 1024 * sizeof(float));
    (void)ws_size;

    // CSR staging aliased onto bufH (only used before first GEMM writes bufH)
    int* srcA = (int*)bufH;
    int* dstA = srcA + Et;

    // ---- dtype detection ----
    detect_kernel<<<1, 256, 0, stream>>>((const unsigned short*)d_in[0],
                                         (const int*)d_in[1], flags);

    // ---- param conversion (weights transposed) ----
    ParamPtrs pp;
    int off = 0;
    {
        int k = 0;
        for (int i = 0; i < 4; ++i) {
            pp.rows[k] = Fin[i]; pp.cols[k] = Fout[i];
            pp.n[k] = Fin[i] * Fout[i]; k++;
            pp.rows[k] = 0; pp.cols[k] = 0; pp.n[k] = Fout[i]; k++;   // a_src
            pp.rows[k] = 0; pp.cols[k] = 0; pp.n[k] = Fout[i]; k++;   // a_dst
            pp.rows[k] = 0; pp.cols[k] = 0; pp.n[k] = Fout[i]; k++;   // b
        }
        pp.rows[16] = 128; pp.cols[16] = 16; pp.n[16] = 128 * 16;     // fc_W
        pp.rows[17] = 0;   pp.cols[17] = 0;  pp.n[17] = 16;           // fc_b
        for (int i = 0; i < 18; ++i) {
            pp.src[i] = d_in[2 + i];
            pp.off[i] = off;
            off += pp.n[i];
        }
    }
    convert_params_kernel<<<18, 256, 0, stream>>>(pp, flags, params);

    const float* Wl[4], *asr[4], *adt[4], *bl[4];
    for (int i = 0; i < 4; ++i) {
        Wl[i]  = params + pp.off[4 * i + 0];
        asr[i] = params + pp.off[4 * i + 1];
        adt[i] = params + pp.off[4 * i + 2];
        bl[i]  = params + pp.off[4 * i + 3];
    }
    const float* fcW = params + pp.off[16];
    const float* fcb = params + pp.off[17];

    const int* e32 = (const int*)d_in[1];

    // ---- CSR build ----
    {
        hipMemsetAsync(deg, 0, (size_t)N * sizeof(int), stream);
        int eblocks = (int)((Et + 255) / 256);
        extract_edges_kernel<<<eblocks, 256, 0, stream>>>(e32, flags, srcA, dstA, E, Et);
        csr_count_kernel<<<eblocks, 256, 0, stream>>>(dstA, deg, Et);

        const int NB = (N + 255) / 256;
        scan_partial_kernel<<<NB, 256, 0, stream>>>(deg, pscan, N);
        scan_mid_kernel<<<1, 64, 0, stream>>>(pscan, pscan + 256, rowptr, NB, N);
        scan_write_kernel<<<NB, 256, 0, stream>>>(deg, pscan + 256, rowptr, fillpos, N);

        int shift = 0;
        while ((N >> shift) > 8) shift++;
        const int chunkSize = 4096;
        const int nchunks = (int)((Et + chunkSize - 1) / chunkSize);
        csr_fill_bucket_kernel<<<nchunks * 8, 256, 0, stream>>>(
            srcA, dstA, fillpos, csr_src, Et, chunkSize, shift);
    }

    // ---- layers ----
    const int gblocks = (N + 3) / 4;
    const void* xin = d_in[0];

    // layer 0: 128 -> 32
    gemm_alpha_kernel<128, 32><<<(N + 7) / 8, dim3(32, 8), 0, stream>>>(
        xin, flags, 1, Wl[0], asr[0], adt[0], nullptr, bufH, as, ad, N, 0, 0);
    gat_gather_kernel<32><<<gblocks, 256, 0, stream>>>(
        rowptr, csr_src, as, ad, bufH, bl[0], bufX, N);

    // layer 1: 32 -> 64
    gemm_alpha_kernel<32, 64><<<(N + 3) / 4, dim3(64, 4), 0, stream>>>(
        bufX, flags, 0, Wl[1], asr[1], adt[1], nullptr, bufH, as, ad, N, 1, 0);
    gat_gather_kernel<64><<<gblocks, 256, 0, stream>>>(
        rowptr, csr_src, as, ad, bufH, bl[1], bufX, N);

    // layer 2: 64 -> 128
    gemm_alpha_kernel<64, 128><<<(N + 1) / 2, dim3(128, 2), 0, stream>>>(
        bufX, flags, 0, Wl[2], asr[2], adt[2], nullptr, bufH, as, ad, N, 1, 0);
    gat_gather_kernel<128><<<gblocks, 256, 0, stream>>>(
        rowptr, csr_src, as, ad, bufH, bl[2], bufX, N);

    // layer 3: 128 -> 128
    gemm_alpha_kernel<128, 128><<<(N + 1) / 2, dim3(128, 2), 0, stream>>>(
        bufX, flags, 0, Wl[3], asr[3], adt[3], nullptr, bufH, as, ad, N, 1, 0);
    gat_gather_kernel<128><<<gblocks, 256, 0, stream>>>(
        rowptr, csr_src, as, ad, bufH, bl[3], bufX, N);

    // final fc: out = relu(x) @ fc_W + fc_b (fp32 out)
    gemm_alpha_kernel<128, 16><<<(N + 15) / 16, dim3(16, 16), 0, stream>>>(
        bufX, flags, 0, fcW, nullptr, nullptr, fcb,
        (float*)d_out, nullptr, nullptr, N, 1, 1);
}

// Round 7
// 836.280 us; speedup vs baseline: 1.5832x; 1.5832x over previous
//
#include <hip/hip_runtime.h>
#include <hip/hip_bf16.h>

// ---------------------------------------------------------------------------
// GAT (4 layers + fc) on MI355X. CSR-gather formulation (no float atomics).
// flags[0]: float tensors bf16(1)/fp32(0); flags[1]: edges int64(1)/int32(0)
// fp32 internal compute, fp32 output.
// R6: reverted weight transpose (lane-coalesced W[k*FOUT+tx] — per-thread-
//     contiguous Wt was a 3x regression: 64 cache lines per load).
//     Keeps: bucketed csr_fill, parallel scan, templated GEMM + gather.
// ---------------------------------------------------------------------------

__device__ __forceinline__ float bf2f(unsigned short w) {
    return __uint_as_float(((unsigned int)w) << 16);
}

// --------------------------- dtype detection -------------------------------
__global__ void detect_kernel(const unsigned short* __restrict__ xw,
                              const int* __restrict__ ew,
                              int* __restrict__ flags)
{
    __shared__ int cnt_sane[256];
    __shared__ int cnt_nz[256];
    const int t = threadIdx.x;
    unsigned short w = xw[2 * t];
    int e = (w >> 7) & 0xff;
    cnt_sane[t] = (e >= 110 && e <= 133) ? 1 : 0;
    cnt_nz[t] = (ew[2 * t + 1] != 0) ? 1 : 0;
    __syncthreads();
    if (t == 0) {
        int s = 0, nz = 0;
        for (int i = 0; i < 256; ++i) { s += cnt_sane[i]; nz += cnt_nz[i]; }
        flags[0] = (s >= 128) ? 1 : 0;
        flags[1] = (nz == 0) ? 1 : 0;
    }
}

// --------------------------- param conversion ------------------------------
struct ParamPtrs {
    const void* src[18];
    int n[18];
    int off[18];
};

__global__ void convert_params_kernel(ParamPtrs pp, const int* __restrict__ flags,
                                      float* __restrict__ out)
{
    const int b = blockIdx.x;
    const int n = pp.n[b];
    const float* fp = (const float*)pp.src[b];
    const unsigned short* hp = (const unsigned short*)pp.src[b];
    const int bf = flags[0];
    float* o = out + pp.off[b];
    for (int i = threadIdx.x; i < n; i += blockDim.x)
        o[i] = bf ? bf2f(hp[i]) : fp[i];
}

// --------------------------- edge extraction -------------------------------
__global__ void extract_edges_kernel(const int* __restrict__ e, const int* __restrict__ flags,
                                     int* __restrict__ srcA, int* __restrict__ dstA,
                                     long long E, long long Et)
{
    long long t = (long long)blockIdx.x * blockDim.x + threadIdx.x;
    if (t >= Et) return;
    int s, d;
    if (t >= E) { s = (int)(t - E); d = s; }
    else if (flags[1]) { s = e[2 * t]; d = e[2 * E + 2 * t]; }
    else               { s = e[t];     d = e[E + t]; }
    srcA[t] = s;
    dstA[t] = d;
}

__global__ void csr_count_kernel(const int* __restrict__ dstA, int* __restrict__ deg,
                                 long long Et)
{
    long long t = (long long)blockIdx.x * blockDim.x + threadIdx.x;
    if (t < Et) atomicAdd(&deg[dstA[t]], 1);
}

// ------------------------------ parallel scan ------------------------------
__global__ void scan_partial_kernel(const int* __restrict__ deg, int* __restrict__ partials,
                                    int N)
{
    __shared__ int sd[256];
    const int t = threadIdx.x;
    const int i = blockIdx.x * 256 + t;
    sd[t] = (i < N) ? deg[i] : 0;
    __syncthreads();
    for (int s = 128; s > 0; s >>= 1) {
        if (t < s) sd[t] += sd[t + s];
        __syncthreads();
    }
    if (t == 0) partials[blockIdx.x] = sd[0];
}

__global__ void scan_mid_kernel(const int* __restrict__ partials, int* __restrict__ pscan,
                                int* __restrict__ rowptr, int NB, int N)
{
    if (threadIdx.x == 0) {
        int a = 0;
        for (int j = 0; j < NB; ++j) { pscan[j] = a; a += partials[j]; }
        rowptr[N] = a;
    }
}

__global__ void scan_write_kernel(const int* __restrict__ deg, const int* __restrict__ pscan,
                                  int* __restrict__ rowptr, int* __restrict__ fillpos, int N)
{
    __shared__ int sd[256];
    const int t = threadIdx.x;
    const int i = blockIdx.x * 256 + t;
    const int v = (i < N) ? deg[i] : 0;
    sd[t] = v;
    __syncthreads();
    for (int off = 1; off < 256; off <<= 1) {
        int x = (t >= off) ? sd[t - off] : 0;
        __syncthreads();
        sd[t] += x;
        __syncthreads();
    }
    const int pos = pscan[blockIdx.x] + sd[t] - v;
    if (i < N) { rowptr[i] = pos; fillpos[i] = pos; }
}

// ------------------------- bucketed CSR fill -------------------------------
// bucket = blockIdx.x & 7 -> round-robin XCD affinity; each bucket's csr_src
// region is dirtied in (heuristically) one XCD L2 -> full-line writebacks.
__global__ __launch_bounds__(256) void csr_fill_bucket_kernel(
    const int* __restrict__ srcA, const int* __restrict__ dstA,
    int* __restrict__ fillpos, int* __restrict__ csr_src,
    long long Et, int chunkSize, int shift)
{
    const int bucket = blockIdx.x & 7;
    const long long c0 = (long long)(blockIdx.x >> 3) * chunkSize;
    const long long c1 = min(c0 + (long long)chunkSize, Et);
    for (long long i = c0 + threadIdx.x; i < c1; i += 256) {
        const int d = dstA[i];
        if ((d >> shift) == bucket) {
            const int pos = atomicAdd(&fillpos[d], 1);
            csr_src[pos] = srcA[i];
        }
    }
}

// ------------------------------- GEMM --------------------------------------
// x:[N,FIN] -> h:[N,FOUT], fused alpha dots. W layout [FIN][FOUT]:
// lane tx reads W[k*FOUT+tx] -> consecutive lanes, consecutive addresses.
template <int FIN, int FOUT>
__global__ __launch_bounds__(256) void gemm_alpha_kernel(
    const void* __restrict__ xv, const int* __restrict__ flags, int x_ext,
    const float* __restrict__ W, const float* __restrict__ a_src,
    const float* __restrict__ a_dst, const float* __restrict__ bias,
    float* __restrict__ h,
    float* __restrict__ alpha_s, float* __restrict__ alpha_d,
    int N, int relu_in, int has_bias)
{
    constexpr int ROWS = 256 / FOUT;
    __shared__ float xs[ROWS * FIN];
    __shared__ float red_s[256];
    __shared__ float red_d[256];

    const int tx = threadIdx.x;
    const int ty = threadIdx.y;
    const int tid = ty * FOUT + tx;
    const long long base_row = (long long)blockIdx.x * ROWS;

    const int xbf = x_ext ? flags[0] : 0;
    const float* xf = (const float*)xv;
    const unsigned short* xh = (const unsigned short*)xv;

    constexpr int total = ROWS * FIN;
    #pragma unroll
    for (int idx = tid; idx < total; idx += 256) {
        const int r = idx / FIN;
        const int c = idx - r * FIN;
        const long long grow = base_row + r;
        float v = 0.f;
        if (grow < N) {
            const long long gi = grow * FIN + c;
            v = xbf ? bf2f(xh[gi]) : xf[gi];
        }
        if (relu_in) v = fmaxf(v, 0.f);
        xs[idx] = v;
    }
    __syncthreads();

    const long long grow = base_row + ty;
    float acc = 0.f;
    #pragma unroll
    for (int k = 0; k < FIN; k += 4) {
        const float4 a = *(const float4*)(xs + ty * FIN + k);
        acc += a.x * W[(k + 0) * FOUT + tx];
        acc += a.y * W[(k + 1) * FOUT + tx];
        acc += a.z * W[(k + 2) * FOUT + tx];
        acc += a.w * W[(k + 3) * FOUT + tx];
    }
    if (has_bias) acc += bias[tx];
    if (grow < N) h[grow * FOUT + tx] = acc;

    if (alpha_s) {
        red_s[tid] = acc * a_src[tx];
        red_d[tid] = acc * a_dst[tx];
        __syncthreads();
        #pragma unroll
        for (int s = FOUT >> 1; s > 0; s >>= 1) {
            if (tx < s) {
                red_s[tid] += red_s[tid + s];
                red_d[tid] += red_d[tid + s];
            }
            __syncthreads();
        }
        if (tx == 0 && grow < N) {
            alpha_s[grow] = red_s[ty * FOUT];
            alpha_d[grow] = red_d[ty * FOUT];
        }
    }
}

// --------------------------- gather (per-dst wave) -------------------------
// One wave per destination node; softmax + weighted sum in registers.
template <int FOUT>
__global__ __launch_bounds__(256) void gat_gather_kernel(
    const int* __restrict__ rowptr, const int* __restrict__ csr_src,
    const float* __restrict__ as, const float* __restrict__ ad,
    const float* __restrict__ h, const float* __restrict__ bias,
    float* __restrict__ out, int N)
{
    const int wslot = threadIdx.x >> 6;
    const int lane = threadIdx.x & 63;
    const int d = blockIdx.x * 4 + wslot;
    if (d >= N) return;

    const int r0 = rowptr[d];
    const int r1 = rowptr[d + 1];
    const float add = ad[d];

    // pass 1: segment max
    float m = -INFINITY;
    for (int base = r0; base < r1; base += 64) {
        const int e = base + lane;
        if (e < r1) {
            const int s = csr_src[e];
            float v = as[s] + add;
            v = (v > 0.f) ? v : 0.2f * v;
            m = fmaxf(m, v);
        }
    }
    #pragma unroll
    for (int off = 32; off > 0; off >>= 1)
        m = fmaxf(m, __shfl_down(m, off, 64));
    m = __shfl(m, 0, 64);

    // pass 2: exp weights + feature accumulation
    constexpr int epi = (FOUT < 64) ? (64 / FOUT) : 1;
    const int sub = (FOUT < 64) ? (lane / FOUT) : 0;
    const int f   = (FOUT < 64) ? (lane % FOUT) : lane;

    float den = 0.f;
    float acc0 = 0.f, acc1 = 0.f;
    for (int base = r0; base < r1; base += 64) {
        const int e = base + lane;
        float p = 0.f;
        int s = 0;
        if (e < r1) {
            s = csr_src[e];
            float v = as[s] + add;
            v = (v > 0.f) ? v : 0.2f * v;
            p = expf(v - m);
        }
        den += p;
        const int cnt = min(64, r1 - base);
        // unroll 4 edge-groups; OOB slots carry p=0 so over-run is harmless
        for (int j = 0; j < cnt; j += 4 * epi) {
            #pragma unroll
            for (int u = 0; u < 4; ++u) {
                const int jj = j + u * epi + sub;
                const float pj = __shfl(p, jj, 64);
                const int   sj = __shfl(s, jj, 64);
                acc0 += pj * h[(long long)sj * FOUT + f];
                if (FOUT == 128) acc1 += pj * h[(long long)sj * FOUT + f + 64];
            }
        }
    }
    #pragma unroll
    for (int off = 32; off > 0; off >>= 1)
        den += __shfl_down(den, off, 64);
    den = __shfl(den, 0, 64);
    const float inv = 1.f / den;

    if (FOUT == 128) {
        out[(long long)d * 128 + lane]      = bias[lane] + acc0 * inv;
        out[(long long)d * 128 + lane + 64] = bias[lane + 64] + acc1 * inv;
    } else if (FOUT == 64) {
        out[(long long)d * 64 + lane] = bias[lane] + acc0 * inv;
    } else {
        acc0 += __shfl_down(acc0, 32, 64);
        if (lane < 32)
            out[(long long)d * 32 + lane] = bias[lane] + acc0 * inv;
    }
}

// ------------------------------- launch ------------------------------------
extern "C" void kernel_launch(void* const* d_in, const int* in_sizes, int n_in,
                              void* d_out, int out_size, void* d_ws, size_t ws_size,
                              hipStream_t stream)
{
    const int INP = 128;
    const int N = in_sizes[0] / INP;                 // 50000
    const long long E = in_sizes[1] / 2;             // 1600000
    const long long Et = E + N;

    const int Fin[4]  = {128, 32, 64, 128};
    const int Fout[4] = {32, 64, 128, 128};

    // ---- workspace layout (~59 MB) ----
    char* p = (char*)d_ws;
    auto alloc = [&](size_t bytes) {
        char* r = p;
        p += (bytes + 255) & ~(size_t)255;
        return r;
    };
    float* bufH    = (float*)alloc((size_t)N * 128 * sizeof(float));
    float* bufX    = (float*)alloc((size_t)N * 128 * sizeof(float));
    float* as      = (float*)alloc((size_t)N * sizeof(float));
    float* ad      = (float*)alloc((size_t)N * sizeof(float));
    int*   deg     = (int*)  alloc((size_t)N * sizeof(int));
    int*   rowptr  = (int*)  alloc((size_t)(N + 1) * sizeof(int));
    int*   fillpos = (int*)  alloc((size_t)N * sizeof(int));
    int*   csr_src = (int*)  alloc((size_t)Et * sizeof(int));
    int*   pscan   = (int*)  alloc(2 * 256 * sizeof(int));
    int*   flags   = (int*)  alloc(64);
    float* params  = (float*)alloc(64 * 1024 * sizeof(float));
    (void)ws_size;

    // CSR staging aliased onto bufH (only used before first GEMM writes bufH)
    int* srcA = (int*)bufH;
    int* dstA = srcA + Et;

    // ---- dtype detection ----
    detect_kernel<<<1, 256, 0, stream>>>((const unsigned short*)d_in[0],
                                         (const int*)d_in[1], flags);

    // ---- param conversion ----
    ParamPtrs pp;
    int off = 0;
    {
        int k = 0;
        for (int i = 0; i < 4; ++i) {
            pp.n[k++] = Fin[i] * Fout[i];
            pp.n[k++] = Fout[i];
            pp.n[k++] = Fout[i];
            pp.n[k++] = Fout[i];
        }
        pp.n[16] = 128 * 16;
        pp.n[17] = 16;
        for (int i = 0; i < 18; ++i) {
            pp.src[i] = d_in[2 + i];
            pp.off[i] = off;
            off += pp.n[i];
        }
    }
    convert_params_kernel<<<18, 256, 0, stream>>>(pp, flags, params);

    const float* Wl[4], *asr[4], *adt[4], *bl[4];
    for (int i = 0; i < 4; ++i) {
        Wl[i]  = params + pp.off[4 * i + 0];
        asr[i] = params + pp.off[4 * i + 1];
        adt[i] = params + pp.off[4 * i + 2];
        bl[i]  = params + pp.off[4 * i + 3];
    }
    const float* fcW = params + pp.off[16];
    const float* fcb = params + pp.off[17];

    const int* e32 = (const int*)d_in[1];

    // ---- CSR build ----
    {
        hipMemsetAsync(deg, 0, (size_t)N * sizeof(int), stream);
        int eblocks = (int)((Et + 255) / 256);
        extract_edges_kernel<<<eblocks, 256, 0, stream>>>(e32, flags, srcA, dstA, E, Et);
        csr_count_kernel<<<eblocks, 256, 0, stream>>>(dstA, deg, Et);

        const int NB = (N + 255) / 256;
        scan_partial_kernel<<<NB, 256, 0, stream>>>(deg, pscan, N);
        scan_mid_kernel<<<1, 64, 0, stream>>>(pscan, pscan + 256, rowptr, NB, N);
        scan_write_kernel<<<NB, 256, 0, stream>>>(deg, pscan + 256, rowptr, fillpos, N);

        int shift = 0;
        while ((N >> shift) > 8) shift++;
        const int chunkSize = 4096;
        const int nchunks = (int)((Et + chunkSize - 1) / chunkSize);
        csr_fill_bucket_kernel<<<nchunks * 8, 256, 0, stream>>>(
            srcA, dstA, fillpos, csr_src, Et, chunkSize, shift);
    }

    // ---- layers ----
    const int gblocks = (N + 3) / 4;
    const void* xin = d_in[0];

    // layer 0: 128 -> 32
    gemm_alpha_kernel<128, 32><<<(N + 7) / 8, dim3(32, 8), 0, stream>>>(
        xin, flags, 1, Wl[0], asr[0], adt[0], nullptr, bufH, as, ad, N, 0, 0);
    gat_gather_kernel<32><<<gblocks, 256, 0, stream>>>(
        rowptr, csr_src, as, ad, bufH, bl[0], bufX, N);

    // layer 1: 32 -> 64
    gemm_alpha_kernel<32, 64><<<(N + 3) / 4, dim3(64, 4), 0, stream>>>(
        bufX, flags, 0, Wl[1], asr[1], adt[1], nullptr, bufH, as, ad, N, 1, 0);
    gat_gather_kernel<64><<<gblocks, 256, 0, stream>>>(
        rowptr, csr_src, as, ad, bufH, bl[1], bufX, N);

    // layer 2: 64 -> 128
    gemm_alpha_kernel<64, 128><<<(N + 1) / 2, dim3(128, 2), 0, stream>>>(
        bufX, flags, 0, Wl[2], asr[2], adt[2], nullptr, bufH, as, ad, N, 1, 0);
    gat_gather_kernel<128><<<gblocks, 256, 0, stream>>>(
        rowptr, csr_src, as, ad, bufH, bl[2], bufX, N);

    // layer 3: 128 -> 128
    gemm_alpha_kernel<128, 128><<<(N + 1) / 2, dim3(128, 2), 0, stream>>>(
        bufX, flags, 0, Wl[3], asr[3], adt[3], nullptr, bufH, as, ad, N, 1, 0);
    gat_gather_kernel<128><<<gblocks, 256, 0, stream>>>(
        rowptr, csr_src, as, ad, bufH, bl[3], bufX, N);

    // final fc: out = relu(x) @ fc_W + fc_b (fp32 out)
    gemm_alpha_kernel<128, 16><<<(N + 15) / 16, dim3(16, 16), 0, stream>>>(
        bufX, flags, 0, fcW, nullptr, nullptr, fcb,
        (float*)d_out, nullptr, nullptr, N, 1, 1);
}

// Round 8
// 708.880 us; speedup vs baseline: 1.8678x; 1.1797x over previous
//
#include <hip/hip_runtime.h>
#include <hip/hip_bf16.h>

// ---------------------------------------------------------------------------
// GAT (4 layers + fc) on MI355X. CSR-gather formulation (no float atomics).
// flags[0]: float tensors bf16(1)/fp32(0); flags[1]: edges int64(1)/int32(0)
// fp32 internal compute, fp32 output.
// R7: register-blocked GEMM (TM=64 rows/block, acc[RR][4]/thread).
//     R6's 2-row blocks re-fetched W from L2 once per thread per k:
//     3.3 GB L2 traffic -> 113 us. Now W amortized over 64 rows (~400 MB).
//     W layout stays [FIN][FOUT] (lane-coalesced; transposed W was 3x slower).
// ---------------------------------------------------------------------------

__device__ __forceinline__ float bf2f(unsigned short w) {
    return __uint_as_float(((unsigned int)w) << 16);
}

// --------------------------- dtype detection -------------------------------
__global__ void detect_kernel(const unsigned short* __restrict__ xw,
                              const int* __restrict__ ew,
                              int* __restrict__ flags)
{
    __shared__ int cnt_sane[256];
    __shared__ int cnt_nz[256];
    const int t = threadIdx.x;
    unsigned short w = xw[2 * t];
    int e = (w >> 7) & 0xff;
    cnt_sane[t] = (e >= 110 && e <= 133) ? 1 : 0;
    cnt_nz[t] = (ew[2 * t + 1] != 0) ? 1 : 0;
    __syncthreads();
    if (t == 0) {
        int s = 0, nz = 0;
        for (int i = 0; i < 256; ++i) { s += cnt_sane[i]; nz += cnt_nz[i]; }
        flags[0] = (s >= 128) ? 1 : 0;
        flags[1] = (nz == 0) ? 1 : 0;
    }
}

// --------------------------- param conversion ------------------------------
struct ParamPtrs {
    const void* src[18];
    int n[18];
    int off[18];
};

__global__ void convert_params_kernel(ParamPtrs pp, const int* __restrict__ flags,
                                      float* __restrict__ out)
{
    const int b = blockIdx.x;
    const int n = pp.n[b];
    const float* fp = (const float*)pp.src[b];
    const unsigned short* hp = (const unsigned short*)pp.src[b];
    const int bf = flags[0];
    float* o = out + pp.off[b];
    for (int i = threadIdx.x; i < n; i += blockDim.x)
        o[i] = bf ? bf2f(hp[i]) : fp[i];
}

// --------------------------- edge extraction -------------------------------
__global__ void extract_edges_kernel(const int* __restrict__ e, const int* __restrict__ flags,
                                     int* __restrict__ srcA, int* __restrict__ dstA,
                                     long long E, long long Et)
{
    long long t = (long long)blockIdx.x * blockDim.x + threadIdx.x;
    if (t >= Et) return;
    int s, d;
    if (t >= E) { s = (int)(t - E); d = s; }
    else if (flags[1]) { s = e[2 * t]; d = e[2 * E + 2 * t]; }
    else               { s = e[t];     d = e[E + t]; }
    srcA[t] = s;
    dstA[t] = d;
}

__global__ void csr_count_kernel(const int* __restrict__ dstA, int* __restrict__ deg,
                                 long long Et)
{
    long long t = (long long)blockIdx.x * blockDim.x + threadIdx.x;
    if (t < Et) atomicAdd(&deg[dstA[t]], 1);
}

// ------------------------------ parallel scan ------------------------------
__global__ void scan_partial_kernel(const int* __restrict__ deg, int* __restrict__ partials,
                                    int N)
{
    __shared__ int sd[256];
    const int t = threadIdx.x;
    const int i = blockIdx.x * 256 + t;
    sd[t] = (i < N) ? deg[i] : 0;
    __syncthreads();
    for (int s = 128; s > 0; s >>= 1) {
        if (t < s) sd[t] += sd[t + s];
        __syncthreads();
    }
    if (t == 0) partials[blockIdx.x] = sd[0];
}

__global__ void scan_mid_kernel(const int* __restrict__ partials, int* __restrict__ pscan,
                                int* __restrict__ rowptr, int NB, int N)
{
    if (threadIdx.x == 0) {
        int a = 0;
        for (int j = 0; j < NB; ++j) { pscan[j] = a; a += partials[j]; }
        rowptr[N] = a;
    }
}

__global__ void scan_write_kernel(const int* __restrict__ deg, const int* __restrict__ pscan,
                                  int* __restrict__ rowptr, int* __restrict__ fillpos, int N)
{
    __shared__ int sd[256];
    const int t = threadIdx.x;
    const int i = blockIdx.x * 256 + t;
    const int v = (i < N) ? deg[i] : 0;
    sd[t] = v;
    __syncthreads();
    for (int off = 1; off < 256; off <<= 1) {
        int x = (t >= off) ? sd[t - off] : 0;
        __syncthreads();
        sd[t] += x;
        __syncthreads();
    }
    const int pos = pscan[blockIdx.x] + sd[t] - v;
    if (i < N) { rowptr[i] = pos; fillpos[i] = pos; }
}

// ------------------------- bucketed CSR fill -------------------------------
__global__ __launch_bounds__(256) void csr_fill_bucket_kernel(
    const int* __restrict__ srcA, const int* __restrict__ dstA,
    int* __restrict__ fillpos, int* __restrict__ csr_src,
    long long Et, int chunkSize, int shift)
{
    const int bucket = blockIdx.x & 7;
    const long long c0 = (long long)(blockIdx.x >> 3) * chunkSize;
    const long long c1 = min(c0 + (long long)chunkSize, Et);
    for (long long i = c0 + threadIdx.x; i < c1; i += 256) {
        const int d = dstA[i];
        if ((d >> shift) == bucket) {
            const int pos = atomicAdd(&fillpos[d], 1);
            csr_src[pos] = srcA[i];
        }
    }
}

// ------------------------------- GEMM --------------------------------------
// x:[N,FIN] -> h:[N,FOUT], fused alpha dots. Register-blocked:
// block = 256 threads, TM=64 rows; thread (cg, rt) computes RR rows x 4 cols.
// W [FIN][FOUT], lane-coalesced float4 loads (L2-resident, amortized 64 rows).
template <int FIN, int FOUT>
__global__ __launch_bounds__(256) void gemm_alpha_kernel(
    const void* __restrict__ xv, const int* __restrict__ flags, int x_ext,
    const float* __restrict__ W, const float* __restrict__ a_src,
    const float* __restrict__ a_dst, const float* __restrict__ bias,
    float* __restrict__ h,
    float* __restrict__ alpha_s, float* __restrict__ alpha_d, int has_alpha,
    int N, int relu_in, int has_bias)
{
    constexpr int CG = FOUT / 4;     // col groups (float4)
    constexpr int RT = 256 / CG;     // row-thread groups
    constexpr int RR = 64 / RT;      // rows per thread
    constexpr int TM = 64;           // rows per block
    constexpr int XP = FIN + 4;      // padded LDS row stride (16B-aligned rows)

    __shared__ float xs[TM * XP];
    __shared__ float red[2][TM][CG + 1];

    const int tx = threadIdx.x;
    const int cg = tx & (CG - 1);
    const int rt = tx / CG;
    const long long base = (long long)blockIdx.x * TM;

    const int xbf = x_ext ? flags[0] : 0;

    // ---- load x tile into LDS (optionally relu) ----
    for (int idx = tx; idx < TM * FIN / 4; idx += 256) {
        const int r  = idx / (FIN / 4);
        const int c4 = idx - r * (FIN / 4);
        const long long grow = base + r;
        float4 v = make_float4(0.f, 0.f, 0.f, 0.f);
        if (grow < N) {
            if (xbf) {
                const unsigned short* xp = (const unsigned short*)xv + grow * FIN + 4 * c4;
                v.x = bf2f(xp[0]); v.y = bf2f(xp[1]);
                v.z = bf2f(xp[2]); v.w = bf2f(xp[3]);
            } else {
                v = *((const float4*)xv + grow * (FIN / 4) + c4);
            }
            if (relu_in) {
                v.x = fmaxf(v.x, 0.f); v.y = fmaxf(v.y, 0.f);
                v.z = fmaxf(v.z, 0.f); v.w = fmaxf(v.w, 0.f);
            }
        }
        *(float4*)&xs[r * XP + 4 * c4] = v;
    }
    __syncthreads();

    // ---- main loop: acc[RR][4] ----
    float acc[RR][4];
    #pragma unroll
    for (int rr = 0; rr < RR; ++rr)
        { acc[rr][0] = acc[rr][1] = acc[rr][2] = acc[rr][3] = 0.f; }

    const int r0 = rt * RR;
    #pragma unroll 4
    for (int k = 0; k < FIN; ++k) {
        const float4 w4 = *(const float4*)(W + k * FOUT + 4 * cg);
        #pragma unroll
        for (int rr = 0; rr < RR; ++rr) {
            const float xval = xs[(r0 + rr) * XP + k];
            acc[rr][0] += xval * w4.x;
            acc[rr][1] += xval * w4.y;
            acc[rr][2] += xval * w4.z;
            acc[rr][3] += xval * w4.w;
        }
    }

    if (has_bias) {
        const float4 b4 = *(const float4*)(bias + 4 * cg);
        #pragma unroll
        for (int rr = 0; rr < RR; ++rr) {
            acc[rr][0] += b4.x; acc[rr][1] += b4.y;
            acc[rr][2] += b4.z; acc[rr][3] += b4.w;
        }
    }

    // ---- store h ----
    #pragma unroll
    for (int rr = 0; rr < RR; ++rr) {
        const long long grow = base + r0 + rr;
        if (grow < N)
            *(float4*)(h + grow * FOUT + 4 * cg) =
                make_float4(acc[rr][0], acc[rr][1], acc[rr][2], acc[rr][3]);
    }

    // ---- fused alpha dots ----
    if (has_alpha) {
        const float4 as4 = *(const float4*)(a_src + 4 * cg);
        const float4 ad4 = *(const float4*)(a_dst + 4 * cg);
        #pragma unroll
        for (int rr = 0; rr < RR; ++rr) {
            red[0][r0 + rr][cg] = acc[rr][0] * as4.x + acc[rr][1] * as4.y
                                + acc[rr][2] * as4.z + acc[rr][3] * as4.w;
            red[1][r0 + rr][cg] = acc[rr][0] * ad4.x + acc[rr][1] * ad4.y
                                + acc[rr][2] * ad4.z + acc[rr][3] * ad4.w;
        }
        __syncthreads();
        if (tx < TM) {
            float ss = 0.f, sd = 0.f;
            #pragma unroll
            for (int j = 0; j < CG; ++j) {
                ss += red[0][tx][j];
                sd += red[1][tx][j];
            }
            const long long grow = base + tx;
            if (grow < N) { alpha_s[grow] = ss; alpha_d[grow] = sd; }
        }
    }
}

// --------------------------- gather (per-dst wave) -------------------------
template <int FOUT>
__global__ __launch_bounds__(256) void gat_gather_kernel(
    const int* __restrict__ rowptr, const int* __restrict__ csr_src,
    const float* __restrict__ as, const float* __restrict__ ad,
    const float* __restrict__ h, const float* __restrict__ bias,
    float* __restrict__ out, int N)
{
    const int wslot = threadIdx.x >> 6;
    const int lane = threadIdx.x & 63;
    const int d = blockIdx.x * 4 + wslot;
    if (d >= N) return;

    const int r0 = rowptr[d];
    const int r1 = rowptr[d + 1];
    const float add = ad[d];

    // pass 1: segment max
    float m = -INFINITY;
    for (int base = r0; base < r1; base += 64) {
        const int e = base + lane;
        if (e < r1) {
            const int s = csr_src[e];
            float v = as[s] + add;
            v = (v > 0.f) ? v : 0.2f * v;
            m = fmaxf(m, v);
        }
    }
    #pragma unroll
    for (int off = 32; off > 0; off >>= 1)
        m = fmaxf(m, __shfl_down(m, off, 64));
    m = __shfl(m, 0, 64);

    // pass 2: exp weights + feature accumulation
    constexpr int epi = (FOUT < 64) ? (64 / FOUT) : 1;
    const int sub = (FOUT < 64) ? (lane / FOUT) : 0;
    const int f   = (FOUT < 64) ? (lane % FOUT) : lane;

    float den = 0.f;
    float acc0 = 0.f, acc1 = 0.f;
    for (int base = r0; base < r1; base += 64) {
        const int e = base + lane;
        float p = 0.f;
        int s = 0;
        if (e < r1) {
            s = csr_src[e];
            float v = as[s] + add;
            v = (v > 0.f) ? v : 0.2f * v;
            p = expf(v - m);
        }
        den += p;
        const int cnt = min(64, r1 - base);
        for (int j = 0; j < cnt; j += 4 * epi) {
            #pragma unroll
            for (int u = 0; u < 4; ++u) {
                const int jj = j + u * epi + sub;
                const float pj = __shfl(p, jj, 64);
                const int   sj = __shfl(s, jj, 64);
                acc0 += pj * h[(long long)sj * FOUT + f];
                if (FOUT == 128) acc1 += pj * h[(long long)sj * FOUT + f + 64];
            }
        }
    }
    #pragma unroll
    for (int off = 32; off > 0; off >>= 1)
        den += __shfl_down(den, off, 64);
    den = __shfl(den, 0, 64);
    const float inv = 1.f / den;

    if (FOUT == 128) {
        out[(long long)d * 128 + lane]      = bias[lane] + acc0 * inv;
        out[(long long)d * 128 + lane + 64] = bias[lane + 64] + acc1 * inv;
    } else if (FOUT == 64) {
        out[(long long)d * 64 + lane] = bias[lane] + acc0 * inv;
    } else {
        acc0 += __shfl_down(acc0, 32, 64);
        if (lane < 32)
            out[(long long)d * 32 + lane] = bias[lane] + acc0 * inv;
    }
}

// ------------------------------- launch ------------------------------------
extern "C" void kernel_launch(void* const* d_in, const int* in_sizes, int n_in,
                              void* d_out, int out_size, void* d_ws, size_t ws_size,
                              hipStream_t stream)
{
    const int INP = 128;
    const int N = in_sizes[0] / INP;                 // 50000
    const long long E = in_sizes[1] / 2;             // 1600000
    const long long Et = E + N;

    const int Fin[4]  = {128, 32, 64, 128};
    const int Fout[4] = {32, 64, 128, 128};

    // ---- workspace layout (~59 MB) ----
    char* p = (char*)d_ws;
    auto alloc = [&](size_t bytes) {
        char* r = p;
        p += (bytes + 255) & ~(size_t)255;
        return r;
    };
    float* bufH    = (float*)alloc((size_t)N * 128 * sizeof(float));
    float* bufX    = (float*)alloc((size_t)N * 128 * sizeof(float));
    float* as      = (float*)alloc((size_t)N * sizeof(float));
    float* ad      = (float*)alloc((size_t)N * sizeof(float));
    int*   deg     = (int*)  alloc((size_t)N * sizeof(int));
    int*   rowptr  = (int*)  alloc((size_t)(N + 1) * sizeof(int));
    int*   fillpos = (int*)  alloc((size_t)N * sizeof(int));
    int*   csr_src = (int*)  alloc((size_t)Et * sizeof(int));
    int*   pscan   = (int*)  alloc(2 * 256 * sizeof(int));
    int*   flags   = (int*)  alloc(64);
    float* params  = (float*)alloc(64 * 1024 * sizeof(float));
    (void)ws_size;

    // CSR staging aliased onto bufH (only used before first GEMM writes bufH)
    int* srcA = (int*)bufH;
    int* dstA = srcA + Et;

    // ---- dtype detection ----
    detect_kernel<<<1, 256, 0, stream>>>((const unsigned short*)d_in[0],
                                         (const int*)d_in[1], flags);

    // ---- param conversion ----
    ParamPtrs pp;
    int off = 0;
    {
        int k = 0;
        for (int i = 0; i < 4; ++i) {
            pp.n[k++] = Fin[i] * Fout[i];
            pp.n[k++] = Fout[i];
            pp.n[k++] = Fout[i];
            pp.n[k++] = Fout[i];
        }
        pp.n[16] = 128 * 16;
        pp.n[17] = 16;
        for (int i = 0; i < 18; ++i) {
            pp.src[i] = d_in[2 + i];
            pp.off[i] = off;
            off += pp.n[i];
        }
    }
    convert_params_kernel<<<18, 256, 0, stream>>>(pp, flags, params);

    const float* Wl[4], *asr[4], *adt[4], *bl[4];
    for (int i = 0; i < 4; ++i) {
        Wl[i]  = params + pp.off[4 * i + 0];
        asr[i] = params + pp.off[4 * i + 1];
        adt[i] = params + pp.off[4 * i + 2];
        bl[i]  = params + pp.off[4 * i + 3];
    }
    const float* fcW = params + pp.off[16];
    const float* fcb = params + pp.off[17];

    const int* e32 = (const int*)d_in[1];

    // ---- CSR build ----
    {
        hipMemsetAsync(deg, 0, (size_t)N * sizeof(int), stream);
        int eblocks = (int)((Et + 255) / 256);
        extract_edges_kernel<<<eblocks, 256, 0, stream>>>(e32, flags, srcA, dstA, E, Et);
        csr_count_kernel<<<eblocks, 256, 0, stream>>>(dstA, deg, Et);

        const int NB = (N + 255) / 256;
        scan_partial_kernel<<<NB, 256, 0, stream>>>(deg, pscan, N);
        scan_mid_kernel<<<1, 64, 0, stream>>>(pscan, pscan + 256, rowptr, NB, N);
        scan_write_kernel<<<NB, 256, 0, stream>>>(deg, pscan + 256, rowptr, fillpos, N);

        int shift = 0;
        while ((N >> shift) > 8) shift++;
        const int chunkSize = 4096;
        const int nchunks = (int)((Et + chunkSize - 1) / chunkSize);
        csr_fill_bucket_kernel<<<nchunks * 8, 256, 0, stream>>>(
            srcA, dstA, fillpos, csr_src, Et, chunkSize, shift);
    }

    // ---- layers ----
    const int gblocks = (N + 3) / 4;
    const int mblocks = (N + 63) / 64;
    const void* xin = d_in[0];

    // layer 0: 128 -> 32
    gemm_alpha_kernel<128, 32><<<mblocks, 256, 0, stream>>>(
        xin, flags, 1, Wl[0], asr[0], adt[0], nullptr, bufH, as, ad, 1, N, 0, 0);
    gat_gather_kernel<32><<<gblocks, 256, 0, stream>>>(
        rowptr, csr_src, as, ad, bufH, bl[0], bufX, N);

    // layer 1: 32 -> 64
    gemm_alpha_kernel<32, 64><<<mblocks, 256, 0, stream>>>(
        bufX, flags, 0, Wl[1], asr[1], adt[1], nullptr, bufH, as, ad, 1, N, 1, 0);
    gat_gather_kernel<64><<<gblocks, 256, 0, stream>>>(
        rowptr, csr_src, as, ad, bufH, bl[1], bufX, N);

    // layer 2: 64 -> 128
    gemm_alpha_kernel<64, 128><<<mblocks, 256, 0, stream>>>(
        bufX, flags, 0, Wl[2], asr[2], adt[2], nullptr, bufH, as, ad, 1, N, 1, 0);
    gat_gather_kernel<128><<<gblocks, 256, 0, stream>>>(
        rowptr, csr_src, as, ad, bufH, bl[2], bufX, N);

    // layer 3: 128 -> 128
    gemm_alpha_kernel<128, 128><<<mblocks, 256, 0, stream>>>(
        bufX, flags, 0, Wl[3], asr[3], adt[3], nullptr, bufH, as, ad, 1, N, 1, 0);
    gat_gather_kernel<128><<<gblocks, 256, 0, stream>>>(
        rowptr, csr_src, as, ad, bufH, bl[3], bufX, N);

    // final fc: out = relu(x) @ fc_W + fc_b (fp32 out)
    gemm_alpha_kernel<128, 16><<<mblocks, 256, 0, stream>>>(
        bufX, flags, 0, fcW, nullptr, nullptr, fcb,
        (float*)d_out, nullptr, nullptr, 0, N, 1, 1);
}